// Round 10
// baseline (251.340 us; speedup 1.0000x reference)
//
#include <hip/hip_runtime.h>
#include <hip/hip_bf16.h>

typedef unsigned short u16;
typedef unsigned int   u32;
typedef __attribute__((ext_vector_type(8))) short bf16x8;
typedef __attribute__((ext_vector_type(4))) float f32x4;

#define NB    16
#define CIN   256
#define TDIM  256
#define VDIM  64
#define PCOL  192          // output columns = C_OUT*NEW_NODES, p = co*64 + j
#define NCHX  256          // x-part K chunks (64 wide each)
#define NCH   259          // + 3 seed chunks ; K = 16576
#define MTOT  4096         // N*T
#define CHUNK_U16 12288    // PCOL*64 bf16 per chunk
#define WT_BYTES ((size_t)NCH * CHUNK_U16 * 2)   // 6,365,184 B

// ---- helpers ---------------------------------------------------------------
__device__ __forceinline__ u16 f2bf(float f) {            // f32 -> bf16 RNE
  u32 u = __builtin_bit_cast(u32, f);
  u32 r = u + 0x7fffu + ((u >> 16) & 1u);
  return (u16)(r >> 16);
}
__device__ __forceinline__ u32 pk2(float a, float b) {
  return (u32)f2bf(a) | ((u32)f2bf(b) << 16);
}
__device__ __forceinline__ void gload_lds16(const void* g, void* l) {
  __builtin_amdgcn_global_load_lds(
      (const __attribute__((address_space(1))) u32*)g,
      (__attribute__((address_space(3))) u32*)l, 16, 0, 0);
}

// ---- kernel 1: W f32 -> bf16 swizzled image; also zeroes arrival counters --
// image granule (16B) within chunk: g = p*8 + (q ^ (p&7)),  q = kk/8
__global__ void prep_w(const float* __restrict__ W, u16* __restrict__ Wt,
                       int* __restrict__ cnt) {
  int u  = blockIdx.x * 256 + threadIdx.x;   // exactly NCH*PCOL*8 units
  if (u < 64) cnt[u] = 0;                    // re-zeroed EVERY launch (replay-safe)
  int q  = u & 7;
  int p  = (u >> 3) % PCOL;
  int ch = u / (PCOL * 8);
  int j = p & 63, co = p >> 6;
  const float* src = W + (size_t)(j * 3 + co) * 16576 + ch * 64 + q * 8;
  float4 fa = *(const float4*)src;
  float4 fb = *(const float4*)(src + 4);
  uint4 v;
  v.x = pk2(fa.x, fa.y); v.y = pk2(fa.z, fa.w);
  v.z = pk2(fb.x, fb.y); v.w = pk2(fb.z, fb.w);
  ((uint4*)Wt)[(size_t)ch * 1536 + p * 8 + (q ^ (p & 7))] = v;
}

// ---- kernel 2: bf16 MFMA GEMM (r8 structure: 512 thr, 2 blk/CU, BK=64,
// A depth-2 reg prefetch, B depth-2 LDS-DMA, two-barrier loop) + FUSED
// last-arriver K-split reduction: partials + device fence + per-mblk atomic;
// the S-th arriver re-reads all S slices (same FP order as the old reduce_k)
// and writes out with bias. Saves the reduce dispatch + its graph gap.
__global__ __launch_bounds__(512, 4)
void gemm_bf16(const float* __restrict__ x, const float* __restrict__ seeds,
               const u16* __restrict__ Wt, float* __restrict__ part,
               float* __restrict__ out, const float* __restrict__ b,
               int* __restrict__ cnt, int S) {
  __shared__ __align__(16) u16 lds[2][16384];   // per buf: A[0,4096) B[4096,16384)
  const int tid  = threadIdx.x;
  const int lane = tid & 63;
  const int wid  = tid >> 6;          // 0..7
  const int wm   = wid >> 2;          // row-half: rows wm*32 + 0..31
  const int wn   = wid & 3;           // col-quarter: cols wn*48 + 0..47
  const int bid  = blockIdx.x;
  int mblk, ksp;
  if (S == 8) { ksp = bid & 7;  mblk = bid >> 3; }   // XCD-pinned split
  else        { mblk = bid & 63; ksp = bid >> 6; }
  const int n  = mblk >> 2;
  const int t0 = (mblk & 3) << 6;
  const int c0 = (NCH * ksp) / S;
  const int c1 = (NCH * (ksp + 1)) / S;

  const int q0 = tid & 7;          // A staging: 8-float unit within row
  const int m0 = tid >> 3;         // A staging: one row per thread (0..63)
  const int lr = lane & 15, lq = lane >> 4;

  f32x4 acc[2][3] = {};

  struct ASet { float4 ra, rb; };
  ASet AX, AY;

  auto Bi = [&](int ch, int buf) {   // 3 x global_load_lds dwordx4 per thread
    const char* gsrc = (const char*)Wt + (size_t)ch * 24576 + wid * 3072 + lane * 16;
    char* lbase = (char*)&lds[buf][4096] + wid * 3072;
    #pragma unroll
    for (int r = 0; r < 3; ++r)
      gload_lds16(gsrc + (size_t)r * 1024, lbase + r * 1024);
  };
  auto Ai = [&](int ch, ASet& s) {   // 2 x global_load_dwordx4 into VGPRs
    const float* a0;
    if (ch < NCHX)
      a0 = x + (((size_t)n * CIN + ch) * TDIM + (t0 + m0)) * VDIM + q0 * 8;
    else
      a0 = seeds + ((size_t)n * TDIM + (t0 + m0)) * 192 + (ch - NCHX) * 64 + q0 * 8;
    s.ra = *(const float4*)a0; s.rb = *(const float4*)(a0 + 4);
  };
  auto CONV = [&](const ASet& s, int buf) {  // bf16-pack + swizzled ds_write
    uint4 v;
    v.x = pk2(s.ra.x, s.ra.y); v.y = pk2(s.ra.z, s.ra.w);
    v.z = pk2(s.rb.x, s.rb.y); v.w = pk2(s.rb.z, s.rb.w);
    ((uint4*)&lds[buf][0])[m0 * 8 + (q0 ^ (m0 & 7))] = v;
  };

  auto COMPUTE = [&](int buf) {
    const u16* L = &lds[buf][0];
    #pragma unroll
    for (int ks = 0; ks < 2; ++ks) {
      const int q = ks * 4 + lq;
      bf16x8 af[2], bfr[3];
      #pragma unroll
      for (int mt = 0; mt < 2; ++mt) {
        int m = wm * 32 + mt * 16 + lr;
        af[mt] = *(const bf16x8*)(L + (m * 8 + (q ^ (m & 7))) * 8);
      }
      #pragma unroll
      for (int nt = 0; nt < 3; ++nt) {
        int p = wn * 48 + nt * 16 + lr;
        bfr[nt] = *(const bf16x8*)(L + 4096 + (p * 8 + (q ^ (p & 7))) * 8);
      }
      #pragma unroll
      for (int mt = 0; mt < 2; ++mt)
        #pragma unroll
        for (int nt = 0; nt < 3; ++nt)
          acc[mt][nt] = __builtin_amdgcn_mfma_f32_16x16x32_bf16(
              af[mt], bfr[nt], acc[mt][nt], 0, 0, 0);
    }
  };

  // ---- prologue: B(c0)->buf0, B(c0+1)->buf1 (DMA); A(c0),A(c0+1)->regs ----
  Bi(c0, 0);
  Ai(c0, AX);
  if (c0 + 1 < c1) { Bi(c0 + 1, 1); Ai(c0 + 1, AY); }
  __builtin_amdgcn_sched_barrier(0);
  CONV(AX, 0);   // auto vmcnt wait for A(c0) regs => older B(c0) DMA drained too
  asm volatile("s_waitcnt lgkmcnt(0)" ::: "memory");
  __builtin_amdgcn_sched_barrier(0);
  __builtin_amdgcn_s_barrier();                 // barrier1
  __builtin_amdgcn_sched_barrier(0);

  // ---- main loop, unrolled x2 (named A-sets; rule #20) --------------------
#define PHASE(PAR, AP, AN)                                                    \
  {                                                                           \
    COMPUTE(PAR);                                                             \
    const bool hasN  = (ch + 1 < c1);                                         \
    const bool hasNN = (ch + 2 < c1);                                         \
    if (!hasN) break;                                                         \
    asm volatile("s_waitcnt lgkmcnt(0)" ::: "memory");                        \
    __builtin_amdgcn_sched_barrier(0);                                        \
    __builtin_amdgcn_s_barrier();               /* barrier2: B buf retired */ \
    __builtin_amdgcn_sched_barrier(0);                                        \
    if (hasNN) { Bi(ch + 2, PAR); Ai(ch + 2, AN); }                           \
    __builtin_amdgcn_sched_barrier(0);                                        \
    CONV(AP, (PAR) ^ 1);    /* auto-wait drains A(ch+1) & older B(ch+1) */    \
    asm volatile("s_waitcnt lgkmcnt(0)" ::: "memory");                        \
    __builtin_amdgcn_sched_barrier(0);                                        \
    __builtin_amdgcn_s_barrier();               /* barrier1 */                \
    __builtin_amdgcn_sched_barrier(0);                                        \
  }

  int ch = c0;
  while (true) {
    PHASE(0, AY, AX)     // compute ch (even parity)
    ++ch;
    PHASE(1, AX, AY)     // compute ch (odd parity)
    ++ch;
  }
#undef PHASE

  // ---- epilogue: C layout col=lane&15, row=(lane>>4)*4+reg [m89/m91] ------
  if (S == 1) {
    #pragma unroll
    for (int mt = 0; mt < 2; ++mt)
      #pragma unroll
      for (int nt = 0; nt < 3; ++nt) {
        int col = wn * 48 + nt * 16 + lr;
        float bv = b[(col & 63) * 3 + (col >> 6)];
        #pragma unroll
        for (int r = 0; r < 4; ++r) {
          int row = mblk * 64 + wm * 32 + mt * 16 + lq * 4 + r;
          out[(size_t)row * PCOL + col] = acc[mt][nt][r] + bv;
        }
      }
    return;
  }

  // partials (no bias)
  float* dbase = part + (size_t)ksp * MTOT * PCOL;
  #pragma unroll
  for (int mt = 0; mt < 2; ++mt)
    #pragma unroll
    for (int nt = 0; nt < 3; ++nt) {
      int col = wn * 48 + nt * 16 + lr;
      #pragma unroll
      for (int r = 0; r < 4; ++r) {
        int row = mblk * 64 + wm * 32 + mt * 16 + lq * 4 + r;
        dbase[(size_t)row * PCOL + col] = acc[mt][nt][r];
      }
    }

  // release: make this block's partial visible device-wide, then arrive
  __threadfence();
  __syncthreads();
  __shared__ int amLast;
  if (tid == 0) amLast = (atomicAdd(cnt + mblk, 1) == S - 1) ? 1 : 0;
  __syncthreads();
  if (amLast) {
    __threadfence();   // acquire: see all S partial slices
    const int nf4 = 64 * PCOL / 4;                    // 3072 float4 per mblk
    const size_t base4 = (size_t)mblk * (64 * PCOL / 4);
    for (int it = tid; it < nf4; it += 512) {
      size_t i4 = base4 + it;
      float4 a = ((const float4*)part)[i4];           // s = 0
      for (int s = 1; s < S; ++s) {                   // fixed order: deterministic
        float4 v = ((const float4*)(part + (size_t)s * MTOT * PCOL))[i4];
        a.x += v.x; a.y += v.y; a.z += v.z; a.w += v.w;
      }
      int p0 = (it * 4) % PCOL;
      a.x += b[((p0 + 0) & 63) * 3 + ((p0 + 0) >> 6)];
      a.y += b[((p0 + 1) & 63) * 3 + ((p0 + 1) >> 6)];
      a.z += b[((p0 + 2) & 63) * 3 + ((p0 + 2) >> 6)];
      a.w += b[((p0 + 3) & 63) * 3 + ((p0 + 3) >> 6)];
      ((float4*)out)[i4] = a;
    }
  }
}

// ---- insurance fallback if ws too small for the Wt image (unlikely) --------
__global__ void fallback_k(const float* __restrict__ x, const float* __restrict__ seeds,
                           const float* __restrict__ W, const float* __restrict__ b,
                           float* __restrict__ out) {
  __shared__ float mk[512];
  int m = blockIdx.x, n = m >> 8, t = m & 255, p = threadIdx.x;
  float acc = 0.f;
  for (int k0 = 0; k0 < 16576; k0 += 512) {
    int kn = min(512, 16576 - k0);
    __syncthreads();
    for (int i = threadIdx.x; i < kn; i += 256) {
      int k = k0 + i;
      mk[i] = (k < 16384)
                ? x[(((size_t)n * 256 + (k >> 6)) * 256 + t) * 64 + (k & 63)]
                : seeds[((size_t)n * 256 + t) * 192 + (k - 16384)];
    }
    __syncthreads();
    if (p < PCOL) {
      const float* wr = W + (size_t)((p & 63) * 3 + (p >> 6)) * 16576 + k0;
      for (int i = 0; i < kn; ++i) acc += mk[i] * wr[i];
    }
  }
  if (p < PCOL) out[(size_t)m * PCOL + p] = acc + b[(p & 63) * 3 + (p >> 6)];
}

extern "C" void kernel_launch(void* const* d_in, const int* in_sizes, int n_in,
                              void* d_out, int out_size, void* d_ws, size_t ws_size,
                              hipStream_t stream) {
  (void)in_sizes; (void)n_in; (void)out_size;
  const float* x     = (const float*)d_in[0];
  const float* seeds = (const float*)d_in[1];
  const float* W     = (const float*)d_in[2];
  const float* b     = (const float*)d_in[3];
  float* out = (float*)d_out;

  if (ws_size < WT_BYTES + 256) {        // no room for bf16 weight image
    fallback_k<<<dim3(MTOT), dim3(256), 0, stream>>>(x, seeds, W, b, out);
    return;
  }
  u16* Wt = (u16*)d_ws;
  int S = 8;                             // K-split; grid = 64*S blocks
  while (S > 1 && WT_BYTES + (size_t)S * MTOT * PCOL * 4 + 256 > ws_size) S >>= 1;
  if (WT_BYTES + (size_t)S * MTOT * PCOL * 4 + 256 > ws_size) S = 1;

  float* part = (float*)((char*)d_ws + WT_BYTES);
  int*   cnt  = (int*)((char*)d_ws + WT_BYTES + (size_t)S * MTOT * PCOL * 4);
  if (S == 1) { part = out; cnt = (int*)((char*)d_ws + WT_BYTES); }

  prep_w<<<dim3((NCH * PCOL * 8) / 256), dim3(256), 0, stream>>>(W, Wt, cnt);
  gemm_bf16<<<dim3(64 * S), dim3(512), 0, stream>>>(x, seeds, Wt, part, out, b, cnt, S);
}

// Round 11
// 81.082 us; speedup vs baseline: 3.0998x; 3.0998x over previous
//
#include <hip/hip_runtime.h>
#include <hip/hip_bf16.h>

typedef unsigned short u16;
typedef unsigned int   u32;
typedef __attribute__((ext_vector_type(8))) short bf16x8;
typedef __attribute__((ext_vector_type(4))) float f32x4;

#define NB    16
#define CIN   256
#define TDIM  256
#define VDIM  64
#define PCOL  192          // output columns = C_OUT*NEW_NODES, p = co*64 + j
#define NCHX  256          // x-part K chunks (64 wide each)
#define NCH   259          // + 3 seed chunks ; K = 16576
#define MTOT  4096         // N*T
#define CHUNK_U16 12288    // PCOL*64 bf16 per chunk
#define WT_BYTES ((size_t)NCH * CHUNK_U16 * 2)   // 6,365,184 B

// ---- helpers ---------------------------------------------------------------
__device__ __forceinline__ u16 f2bf(float f) {            // f32 -> bf16 RNE
  u32 u = __builtin_bit_cast(u32, f);
  u32 r = u + 0x7fffu + ((u >> 16) & 1u);
  return (u16)(r >> 16);
}
__device__ __forceinline__ u32 pk2(float a, float b) {
  return (u32)f2bf(a) | ((u32)f2bf(b) << 16);
}
__device__ __forceinline__ void gload_lds16(const void* g, void* l) {
  __builtin_amdgcn_global_load_lds(
      (const __attribute__((address_space(1))) u32*)g,
      (__attribute__((address_space(3))) u32*)l, 16, 0, 0);
}

// ---- kernel 1: W f32 -> bf16, LDS-image layout with baked XOR swizzle ------
// image granule (16B) within chunk: g = p*8 + (q ^ (p&7)),  q = kk/8
__global__ void prep_w(const float* __restrict__ W, u16* __restrict__ Wt) {
  int u  = blockIdx.x * 256 + threadIdx.x;   // exactly NCH*PCOL*8 units
  int q  = u & 7;
  int p  = (u >> 3) % PCOL;
  int ch = u / (PCOL * 8);
  int j = p & 63, co = p >> 6;
  const float* src = W + (size_t)(j * 3 + co) * 16576 + ch * 64 + q * 8;
  float4 fa = *(const float4*)src;
  float4 fb = *(const float4*)(src + 4);
  uint4 v;
  v.x = pk2(fa.x, fa.y); v.y = pk2(fa.z, fa.w);
  v.z = pk2(fb.x, fb.y); v.w = pk2(fb.z, fb.w);
  ((uint4*)Wt)[(size_t)ch * 1536 + p * 8 + (q ^ (p & 7))] = v;
}

// ---- kernel 2: bf16 MFMA GEMM. A: depth-2 reg prefetch (T14). B: depth-2
// LDS DMA via two-barrier loop — barrier2 (lgkm-only, cheap) retires the
// just-read B buffer so B(ch+2) DMA gets ~1.7 iterations of latency cover.
// No explicit vmcnt in the loop: CONV's compiler-inserted wait for A(ch+1)
// regs drains the older B(ch+1) DMA in the in-order vmcnt queue.
__global__ __launch_bounds__(256, 2)
void gemm_bf16(const float* __restrict__ x, const float* __restrict__ seeds,
               const u16* __restrict__ Wt, float* __restrict__ dst,
               const float* __restrict__ bias, int S) {
  __shared__ __align__(16) u16 lds[2][16384];   // per buf: A[0,4096) B[4096,16384)
  const int tid  = threadIdx.x;
  const int lane = tid & 63;
  const int wid  = tid >> 6;
  const int bid  = blockIdx.x;
  int mblk, ksp;
  if (S == 8) { ksp = bid & 7;  mblk = bid >> 3; }   // XCD-pinned split
  else        { mblk = bid & 63; ksp = bid >> 6; }
  const int n  = mblk >> 2;
  const int t0 = (mblk & 3) << 6;
  const int c0 = (NCH * ksp) / S;
  const int c1 = (NCH * (ksp + 1)) / S;

  const int q0 = tid & 7;          // A staging: 8-float unit within row
  const int m0 = tid >> 3;         // A staging: rows m0, m0+32
  const int lr = lane & 15, lq = lane >> 4;

  f32x4 acc[4][3] = {};

  struct ASet { float4 r0a, r0b, r1a, r1b; };
  ASet AX, AY;

  auto Bi = [&](int ch, int buf) {   // 6 x global_load_lds dwordx4 (24KB)
    const char* gsrc = (const char*)Wt + (size_t)ch * 24576 + wid * 1024 + lane * 16;
    char* lbase = (char*)&lds[buf][4096] + wid * 1024;
    #pragma unroll
    for (int r = 0; r < 6; ++r)
      gload_lds16(gsrc + (size_t)r * 4096, lbase + r * 4096);
  };
  auto Ai = [&](int ch, ASet& s) {   // 4 x global_load_dwordx4 into VGPRs
    const float *a0, *a1;
    if (ch < NCHX) {
      a0 = x + (((size_t)n * CIN + ch) * TDIM + (t0 + m0)) * VDIM + q0 * 8;
      a1 = a0 + (size_t)32 * VDIM;
    } else {
      a0 = seeds + ((size_t)n * TDIM + (t0 + m0)) * 192 + (ch - NCHX) * 64 + q0 * 8;
      a1 = a0 + (size_t)32 * 192;
    }
    s.r0a = *(const float4*)a0; s.r0b = *(const float4*)(a0 + 4);
    s.r1a = *(const float4*)a1; s.r1b = *(const float4*)(a1 + 4);
  };
  auto CONV = [&](const ASet& s, int buf) {  // bf16-pack + swizzled ds_write
    uint4 v;
    v.x = pk2(s.r0a.x, s.r0a.y); v.y = pk2(s.r0a.z, s.r0a.w);
    v.z = pk2(s.r0b.x, s.r0b.y); v.w = pk2(s.r0b.z, s.r0b.w);
    ((uint4*)&lds[buf][0])[m0 * 8 + (q0 ^ (m0 & 7))] = v;
    int m1 = m0 + 32;
    v.x = pk2(s.r1a.x, s.r1a.y); v.y = pk2(s.r1a.z, s.r1a.w);
    v.z = pk2(s.r1b.x, s.r1b.y); v.w = pk2(s.r1b.z, s.r1b.w);
    ((uint4*)&lds[buf][0])[m1 * 8 + (q0 ^ (m1 & 7))] = v;
  };

  auto COMPUTE = [&](int buf) {
    const u16* L = &lds[buf][0];
    #pragma unroll
    for (int ks = 0; ks < 2; ++ks) {
      const int q = ks * 4 + lq;
      bf16x8 af[4], bfr[3];
      #pragma unroll
      for (int mt = 0; mt < 4; ++mt) {
        int m = mt * 16 + lr;
        af[mt] = *(const bf16x8*)(L + (m * 8 + (q ^ (m & 7))) * 8);
      }
      #pragma unroll
      for (int nt = 0; nt < 3; ++nt) {
        int p = wid * 48 + nt * 16 + lr;
        bfr[nt] = *(const bf16x8*)(L + 4096 + (p * 8 + (q ^ (p & 7))) * 8);
      }
      #pragma unroll
      for (int mt = 0; mt < 4; ++mt)
        #pragma unroll
        for (int nt = 0; nt < 3; ++nt)
          acc[mt][nt] = __builtin_amdgcn_mfma_f32_16x16x32_bf16(
              af[mt], bfr[nt], acc[mt][nt], 0, 0, 0);
    }
  };

  // ---- prologue: B(c0)->buf0, B(c0+1)->buf1 (DMA); A(c0),A(c0+1)->regs ----
  Bi(c0, 0);
  Ai(c0, AX);
  if (c0 + 1 < c1) { Bi(c0 + 1, 1); Ai(c0 + 1, AY); }
  __builtin_amdgcn_sched_barrier(0);
  CONV(AX, 0);   // auto vmcnt wait for A(c0) regs => older B(c0) DMA drained too
  asm volatile("s_waitcnt lgkmcnt(0)" ::: "memory");
  __builtin_amdgcn_sched_barrier(0);
  __builtin_amdgcn_s_barrier();                 // barrier1
  __builtin_amdgcn_sched_barrier(0);

  // ---- main loop, unrolled x2 (named A-sets; rule #20) --------------------
  // iter ch (parity P=(ch-c0)&1): COMPUTE(P); barrier2; DMA B(ch+2)->P;
  // load A(ch+2)->AN; CONV A(ch+1)->P^1; barrier1.
#define PHASE(PAR, AP, AN)                                                    \
  {                                                                           \
    COMPUTE(PAR);                                                             \
    const bool hasN  = (ch + 1 < c1);                                         \
    const bool hasNN = (ch + 2 < c1);                                         \
    if (!hasN) break;                                                         \
    asm volatile("s_waitcnt lgkmcnt(0)" ::: "memory");                        \
    __builtin_amdgcn_sched_barrier(0);                                        \
    __builtin_amdgcn_s_barrier();               /* barrier2: B buf retired */ \
    __builtin_amdgcn_sched_barrier(0);                                        \
    if (hasNN) { Bi(ch + 2, PAR); Ai(ch + 2, AN); }                           \
    __builtin_amdgcn_sched_barrier(0);                                        \
    CONV(AP, (PAR) ^ 1);    /* auto-wait drains A(ch+1) & older B(ch+1) */    \
    asm volatile("s_waitcnt lgkmcnt(0)" ::: "memory");                        \
    __builtin_amdgcn_sched_barrier(0);                                        \
    __builtin_amdgcn_s_barrier();               /* barrier1 */                \
    __builtin_amdgcn_sched_barrier(0);                                        \
  }

  int ch = c0;
  while (true) {
    PHASE(0, AY, AX)     // compute ch (even parity)
    ++ch;
    PHASE(1, AX, AY)     // compute ch (odd parity)
    ++ch;
  }
#undef PHASE

  // epilogue: C layout col=lane&15, row=(lane>>4)*4+reg  [measured m89/m91]
  float* dbase = dst + (size_t)ksp * MTOT * PCOL;
  #pragma unroll
  for (int mt = 0; mt < 4; ++mt)
    #pragma unroll
    for (int nt = 0; nt < 3; ++nt) {
      int col = wid * 48 + nt * 16 + lr;
      float bv = bias ? bias[(col & 63) * 3 + (col >> 6)] : 0.f;
      #pragma unroll
      for (int r = 0; r < 4; ++r) {
        int row = mblk * 64 + mt * 16 + lq * 4 + r;
        dbase[(size_t)row * PCOL + col] = acc[mt][nt][r] + bv;
      }
    }
}

// ---- kernel 3: deterministic K-split reduction + bias ----------------------
__global__ void reduce_k(const float* __restrict__ part, const float* __restrict__ b,
                         float* __restrict__ out, int S) {
  int i4 = (blockIdx.x * 256 + threadIdx.x) * 4;   // exact: MTOT*PCOL/4 threads
  float4 a = *(const float4*)&part[i4];
  for (int s = 1; s < S; ++s) {
    const float4 v = *(const float4*)&part[(size_t)s * (MTOT * PCOL) + i4];
    a.x += v.x; a.y += v.y; a.z += v.z; a.w += v.w;
  }
  int p0 = i4 % PCOL;
  a.x += b[((p0 + 0) & 63) * 3 + ((p0 + 0) >> 6)];
  a.y += b[((p0 + 1) & 63) * 3 + ((p0 + 1) >> 6)];
  a.z += b[((p0 + 2) & 63) * 3 + ((p0 + 2) >> 6)];
  a.w += b[((p0 + 3) & 63) * 3 + ((p0 + 3) >> 6)];
  *(float4*)&out[i4] = a;
}

// ---- insurance fallback if ws too small for the Wt image (unlikely) --------
__global__ void fallback_k(const float* __restrict__ x, const float* __restrict__ seeds,
                           const float* __restrict__ W, const float* __restrict__ b,
                           float* __restrict__ out) {
  __shared__ float mk[512];
  int m = blockIdx.x, n = m >> 8, t = m & 255, p = threadIdx.x;
  float acc = 0.f;
  for (int k0 = 0; k0 < 16576; k0 += 512) {
    int kn = min(512, 16576 - k0);
    __syncthreads();
    for (int i = threadIdx.x; i < kn; i += 256) {
      int k = k0 + i;
      mk[i] = (k < 16384)
                ? x[(((size_t)n * 256 + (k >> 6)) * 256 + t) * 64 + (k & 63)]
                : seeds[((size_t)n * 256 + t) * 192 + (k - 16384)];
    }
    __syncthreads();
    if (p < PCOL) {
      const float* wr = W + (size_t)((p & 63) * 3 + (p >> 6)) * 16576 + k0;
      for (int i = 0; i < kn; ++i) acc += mk[i] * wr[i];
    }
  }
  if (p < PCOL) out[(size_t)m * PCOL + p] = acc + b[(p & 63) * 3 + (p >> 6)];
}

extern "C" void kernel_launch(void* const* d_in, const int* in_sizes, int n_in,
                              void* d_out, int out_size, void* d_ws, size_t ws_size,
                              hipStream_t stream) {
  (void)in_sizes; (void)n_in; (void)out_size;
  const float* x     = (const float*)d_in[0];
  const float* seeds = (const float*)d_in[1];
  const float* W     = (const float*)d_in[2];
  const float* b     = (const float*)d_in[3];
  float* out = (float*)d_out;

  if (ws_size < WT_BYTES) {              // no room for bf16 weight image
    fallback_k<<<dim3(MTOT), dim3(256), 0, stream>>>(x, seeds, W, b, out);
    return;
  }
  u16* Wt = (u16*)d_ws;
  int S = 8;                             // K-split for grid = 64*S blocks
  while (S > 1 && WT_BYTES + (size_t)S * MTOT * PCOL * 4 > ws_size) S >>= 1;
  if (WT_BYTES + (size_t)S * MTOT * PCOL * 4 > ws_size) S = 1;

  prep_w<<<dim3((NCH * PCOL * 8) / 256), dim3(256), 0, stream>>>(W, Wt);
  if (S == 1) {
    gemm_bf16<<<dim3(64), dim3(256), 0, stream>>>(x, seeds, Wt, out, b, 1);
  } else {
    float* part = (float*)((char*)d_ws + WT_BYTES);
    gemm_bf16<<<dim3(64 * S), dim3(256), 0, stream>>>(x, seeds, Wt, part, nullptr, S);
    reduce_k<<<dim3(MTOT * PCOL / 4 / 256), dim3(256), 0, stream>>>(part, b, out, S);
  }
}

// Round 12
// 80.710 us; speedup vs baseline: 3.1141x; 1.0046x over previous
//
#include <hip/hip_runtime.h>
#include <hip/hip_bf16.h>

typedef unsigned short u16;
typedef unsigned int   u32;
typedef __attribute__((ext_vector_type(8))) short bf16x8;
typedef __attribute__((ext_vector_type(4))) float f32x4;

#define NB    16
#define CIN   256
#define TDIM  256
#define VDIM  64
#define PCOL  192          // output columns = C_OUT*NEW_NODES, p = co*64 + j
#define NCHX  256          // x-part K chunks (64 wide each)
#define NCH   259          // + 3 seed chunks ; K = 16576
#define MTOT  4096         // N*T
#define CHUNK_U16 12288    // PCOL*64 bf16 per chunk
#define WT_BYTES ((size_t)NCH * CHUNK_U16 * 2)   // 6,365,184 B

// ---- helpers ---------------------------------------------------------------
__device__ __forceinline__ u16 f2bf(float f) {            // f32 -> bf16 RNE
  u32 u = __builtin_bit_cast(u32, f);
  u32 r = u + 0x7fffu + ((u >> 16) & 1u);
  return (u16)(r >> 16);
}
__device__ __forceinline__ u32 pk2(float a, float b) {
  return (u32)f2bf(a) | ((u32)f2bf(b) << 16);
}

// ---- kernel 1: W f32 -> bf16, WAVE-LOAD-ORDER image ------------------------
// Image granule (16B) position = [ch][wid][r][lane] where the wave's MFMA
// B-fragment for (nt,ks) at lane l (lr=l&15, lq=l>>4) is p=wid*48+nt*16+lr,
// q=ks*4+lq, r=nt*2+ks. Each of the 6 per-wave loads in the GEMM is then ONE
// contiguous 1KB segment (fixes r6's 128B-strided half-density splitting).
__global__ void prep_w(const float* __restrict__ W, u16* __restrict__ Wt) {
  int u  = blockIdx.x * 256 + threadIdx.x;   // exactly NCH*PCOL*8 units
  int q  = u & 7;
  int p  = (u >> 3) % PCOL;
  int ch = u / (PCOL * 8);
  int j = p & 63, co = p >> 6;
  const float* src = W + (size_t)(j * 3 + co) * 16576 + ch * 64 + q * 8;
  float4 fa = *(const float4*)src;
  float4 fb = *(const float4*)(src + 4);
  uint4 v;
  v.x = pk2(fa.x, fa.y); v.y = pk2(fa.z, fa.w);
  v.z = pk2(fb.x, fb.y); v.w = pk2(fb.z, fb.w);
  int wid = p / 48, within = p % 48;
  int nt = within >> 4, lr = within & 15;
  int ks = q >> 2,      lq = q & 3;
  int r = nt * 2 + ks, lane = lq * 16 + lr;
  ((uint4*)Wt)[(size_t)ch * 1536 + wid * 384 + r * 64 + lane] = v;
}

// ---- kernel 2: bf16 MFMA GEMM. A: LDS double-buffer + depth-2 reg prefetch
// (T14). B: pure-register path via wave-ordered Wt image — 6 fully-coalesced
// 1KB loads/wave/chunk straight to VGPRs, ~2 iterations of latency slack.
// ONE barrier per iteration (only A's LDS needs sync); no vmcnt drains.
__global__ __launch_bounds__(256, 2)
void gemm_bf16(const float* __restrict__ x, const float* __restrict__ seeds,
               const u16* __restrict__ Wt, float* __restrict__ dst,
               const float* __restrict__ bias, int S) {
  __shared__ __align__(16) u16 ldsA[2][4096];   // per buf: 64x64 bf16 A tile
  const int tid  = threadIdx.x;
  const int lane = tid & 63;
  const int wid  = tid >> 6;
  const int bid  = blockIdx.x;
  int mblk, ksp;
  if (S == 8) { ksp = bid & 7;  mblk = bid >> 3; }   // XCD-pinned split
  else        { mblk = bid & 63; ksp = bid >> 6; }
  const int n  = mblk >> 2;
  const int t0 = (mblk & 3) << 6;
  const int c0 = (NCH * ksp) / S;
  const int c1 = (NCH * (ksp + 1)) / S;

  const int q0 = tid & 7;          // A staging: 8-float unit within row
  const int m0 = tid >> 3;         // A staging: rows m0, m0+32
  const int lr = lane & 15, lq = lane >> 4;

  f32x4 acc[4][3] = {};

  struct ASet { float4 r0a, r0b, r1a, r1b; };
  struct BSet { uint4 r0, r1, r2, r3, r4, r5; };   // r = nt*2 + ks
  ASet AX, AY;
  BSet BX, BY;

  const char* bbase = (const char*)Wt + wid * 6144 + lane * 16;

  auto Bi = [&](int ch, BSet& s) {   // 6 coalesced 1KB/wave loads -> VGPRs
    const uint4* g = (const uint4*)(bbase + (size_t)ch * 24576);
    s.r0 = g[0];   s.r1 = g[64];  s.r2 = g[128];
    s.r3 = g[192]; s.r4 = g[256]; s.r5 = g[320];
  };
  auto Ai = [&](int ch, ASet& s) {   // 4 x global_load_dwordx4 into VGPRs
    const float *a0, *a1;
    if (ch < NCHX) {
      a0 = x + (((size_t)n * CIN + ch) * TDIM + (t0 + m0)) * VDIM + q0 * 8;
      a1 = a0 + (size_t)32 * VDIM;
    } else {
      a0 = seeds + ((size_t)n * TDIM + (t0 + m0)) * 192 + (ch - NCHX) * 64 + q0 * 8;
      a1 = a0 + (size_t)32 * 192;
    }
    s.r0a = *(const float4*)a0; s.r0b = *(const float4*)(a0 + 4);
    s.r1a = *(const float4*)a1; s.r1b = *(const float4*)(a1 + 4);
  };
  auto CONV = [&](const ASet& s, int buf) {  // bf16-pack + swizzled ds_write
    uint4 v;
    v.x = pk2(s.r0a.x, s.r0a.y); v.y = pk2(s.r0a.z, s.r0a.w);
    v.z = pk2(s.r0b.x, s.r0b.y); v.w = pk2(s.r0b.z, s.r0b.w);
    ((uint4*)&ldsA[buf][0])[m0 * 8 + (q0 ^ (m0 & 7))] = v;
    int m1 = m0 + 32;
    v.x = pk2(s.r1a.x, s.r1a.y); v.y = pk2(s.r1a.z, s.r1a.w);
    v.z = pk2(s.r1b.x, s.r1b.y); v.w = pk2(s.r1b.z, s.r1b.w);
    ((uint4*)&ldsA[buf][0])[m1 * 8 + (q0 ^ (m1 & 7))] = v;
  };

  auto COMPUTE = [&](int buf, const BSet& B) {
    const u16* L = &ldsA[buf][0];
    #pragma unroll
    for (int ks = 0; ks < 2; ++ks) {
      const int q = ks * 4 + lq;
      bf16x8 af[4];
      #pragma unroll
      for (int mt = 0; mt < 4; ++mt) {
        int m = mt * 16 + lr;
        af[mt] = *(const bf16x8*)(L + (m * 8 + (q ^ (m & 7))) * 8);
      }
      bf16x8 b0 = __builtin_bit_cast(bf16x8, ks ? B.r1 : B.r0);
      bf16x8 b1 = __builtin_bit_cast(bf16x8, ks ? B.r3 : B.r2);
      bf16x8 b2 = __builtin_bit_cast(bf16x8, ks ? B.r5 : B.r4);
      #pragma unroll
      for (int mt = 0; mt < 4; ++mt) {
        acc[mt][0] = __builtin_amdgcn_mfma_f32_16x16x32_bf16(af[mt], b0, acc[mt][0], 0, 0, 0);
        acc[mt][1] = __builtin_amdgcn_mfma_f32_16x16x32_bf16(af[mt], b1, acc[mt][1], 0, 0, 0);
        acc[mt][2] = __builtin_amdgcn_mfma_f32_16x16x32_bf16(af[mt], b2, acc[mt][2], 0, 0, 0);
      }
    }
  };

  // ---- prologue: B(c0),B(c0+1)->regs; A(c0),A(c0+1)->regs; CONV A(c0) -----
  Bi(c0, BX);
  Ai(c0, AX);
  if (c0 + 1 < c1) { Bi(c0 + 1, BY); Ai(c0 + 1, AY); }
  __builtin_amdgcn_sched_barrier(0);
  CONV(AX, 0);                       // compiler auto-waits A(c0) loads
  asm volatile("s_waitcnt lgkmcnt(0)" ::: "memory");
  __builtin_amdgcn_sched_barrier(0);
  __builtin_amdgcn_s_barrier();
  __builtin_amdgcn_sched_barrier(0);

  // ---- main loop, unrolled x2 (named reg-sets; rule #20) ------------------
#define PHASE(PAR, AP, AN, BC)                                                \
  {                                                                           \
    const bool hasN  = (ch + 1 < c1);                                         \
    const bool hasNN = (ch + 2 < c1);                                         \
    if (hasNN) Ai(ch + 2, AN);                                                \
    __builtin_amdgcn_sched_barrier(0);                                        \
    COMPUTE(PAR, BC);                                                         \
    __builtin_amdgcn_sched_barrier(0);                                        \
    if (hasNN) Bi(ch + 2, BC);     /* reload just-consumed set */             \
    if (!hasN) break;                                                         \
    CONV(AP, (PAR) ^ 1);    /* auto-wait drains A(ch+1) regs */               \
    asm volatile("s_waitcnt lgkmcnt(0)" ::: "memory");                        \
    __builtin_amdgcn_sched_barrier(0);                                        \
    __builtin_amdgcn_s_barrier();                                             \
    __builtin_amdgcn_sched_barrier(0);                                        \
  }

  int ch = c0;
  while (true) {
    PHASE(0, AY, AX, BX)     // compute ch (even parity)
    ++ch;
    PHASE(1, AX, AY, BY)     // compute ch (odd parity)
    ++ch;
  }
#undef PHASE

  // epilogue: C layout col=lane&15, row=(lane>>4)*4+reg  [measured m89/m91]
  float* dbase = dst + (size_t)ksp * MTOT * PCOL;
  #pragma unroll
  for (int mt = 0; mt < 4; ++mt)
    #pragma unroll
    for (int nt = 0; nt < 3; ++nt) {
      int col = wid * 48 + nt * 16 + lr;
      float bv = bias ? bias[(col & 63) * 3 + (col >> 6)] : 0.f;
      #pragma unroll
      for (int r = 0; r < 4; ++r) {
        int row = mblk * 64 + mt * 16 + lq * 4 + r;
        dbase[(size_t)row * PCOL + col] = acc[mt][nt][r] + bv;
      }
    }
}

// ---- kernel 3: deterministic K-split reduction + bias ----------------------
__global__ void reduce_k(const float* __restrict__ part, const float* __restrict__ b,
                         float* __restrict__ out, int S) {
  int i4 = (blockIdx.x * 256 + threadIdx.x) * 4;   // exact: MTOT*PCOL/4 threads
  float4 a = *(const float4*)&part[i4];
  for (int s = 1; s < S; ++s) {
    const float4 v = *(const float4*)&part[(size_t)s * (MTOT * PCOL) + i4];
    a.x += v.x; a.y += v.y; a.z += v.z; a.w += v.w;
  }
  int p0 = i4 % PCOL;
  a.x += b[((p0 + 0) & 63) * 3 + ((p0 + 0) >> 6)];
  a.y += b[((p0 + 1) & 63) * 3 + ((p0 + 1) >> 6)];
  a.z += b[((p0 + 2) & 63) * 3 + ((p0 + 2) >> 6)];
  a.w += b[((p0 + 3) & 63) * 3 + ((p0 + 3) >> 6)];
  *(float4*)&out[i4] = a;
}

// ---- insurance fallback if ws too small for the Wt image (unlikely) --------
__global__ void fallback_k(const float* __restrict__ x, const float* __restrict__ seeds,
                           const float* __restrict__ W, const float* __restrict__ b,
                           float* __restrict__ out) {
  __shared__ float mk[512];
  int m = blockIdx.x, n = m >> 8, t = m & 255, p = threadIdx.x;
  float acc = 0.f;
  for (int k0 = 0; k0 < 16576; k0 += 512) {
    int kn = min(512, 16576 - k0);
    __syncthreads();
    for (int i = threadIdx.x; i < kn; i += 256) {
      int k = k0 + i;
      mk[i] = (k < 16384)
                ? x[(((size_t)n * 256 + (k >> 6)) * 256 + t) * 64 + (k & 63)]
                : seeds[((size_t)n * 256 + t) * 192 + (k - 16384)];
    }
    __syncthreads();
    if (p < PCOL) {
      const float* wr = W + (size_t)((p & 63) * 3 + (p >> 6)) * 16576 + k0;
      for (int i = 0; i < kn; ++i) acc += mk[i] * wr[i];
    }
  }
  if (p < PCOL) out[(size_t)m * PCOL + p] = acc + b[(p & 63) * 3 + (p >> 6)];
}

extern "C" void kernel_launch(void* const* d_in, const int* in_sizes, int n_in,
                              void* d_out, int out_size, void* d_ws, size_t ws_size,
                              hipStream_t stream) {
  (void)in_sizes; (void)n_in; (void)out_size;
  const float* x     = (const float*)d_in[0];
  const float* seeds = (const float*)d_in[1];
  const float* W     = (const float*)d_in[2];
  const float* b     = (const float*)d_in[3];
  float* out = (float*)d_out;

  if (ws_size < WT_BYTES) {              // no room for bf16 weight image
    fallback_k<<<dim3(MTOT), dim3(256), 0, stream>>>(x, seeds, W, b, out);
    return;
  }
  u16* Wt = (u16*)d_ws;
  int S = 8;                             // K-split for grid = 64*S blocks
  while (S > 1 && WT_BYTES + (size_t)S * MTOT * PCOL * 4 > ws_size) S >>= 1;
  if (WT_BYTES + (size_t)S * MTOT * PCOL * 4 > ws_size) S = 1;

  prep_w<<<dim3((NCH * PCOL * 8) / 256), dim3(256), 0, stream>>>(W, Wt);
  if (S == 1) {
    gemm_bf16<<<dim3(64), dim3(256), 0, stream>>>(x, seeds, Wt, out, b, 1);
  } else {
    float* part = (float*)((char*)d_ws + WT_BYTES);
    gemm_bf16<<<dim3(64 * S), dim3(256), 0, stream>>>(x, seeds, Wt, part, nullptr, S);
    reduce_k<<<dim3(MTOT * PCOL / 4 / 256), dim3(256), 0, stream>>>(part, b, out, S);
  }
}

// Round 13
// 78.113 us; speedup vs baseline: 3.2176x; 1.0332x over previous
//
#include <hip/hip_runtime.h>
#include <hip/hip_bf16.h>

typedef unsigned short u16;
typedef unsigned int   u32;
typedef __attribute__((ext_vector_type(8))) short bf16x8;
typedef __attribute__((ext_vector_type(4))) float f32x4;

#define NB    16
#define CIN   256
#define TDIM  256
#define VDIM  64
#define PCOL  192          // output columns = C_OUT*NEW_NODES, p = co*64 + j
#define NCHX  256          // x-part K chunks (64 wide each)
#define NCH   259          // + 3 seed chunks ; K = 16576
#define MTOT  4096         // N*T
#define CHUNK_U16 12288    // PCOL*64 bf16 per chunk
#define WT_BYTES ((size_t)NCH * CHUNK_U16 * 2)   // 6,365,184 B

// ---- helpers ---------------------------------------------------------------
__device__ __forceinline__ u16 f2bf(float f) {            // f32 -> bf16 RNE
  u32 u = __builtin_bit_cast(u32, f);
  u32 r = u + 0x7fffu + ((u >> 16) & 1u);
  return (u16)(r >> 16);
}
__device__ __forceinline__ u32 pk2(float a, float b) {
  return (u32)f2bf(a) | ((u32)f2bf(b) << 16);
}

// ---- kernel 1: W f32 -> bf16, WAVE-LOAD-ORDER image (unchanged from r12) ---
// granule position = [ch][wid][r=nt*2+ks][lane]; each per-wave GEMM B-load is
// one contiguous 1KB segment.
__global__ void prep_w(const float* __restrict__ W, u16* __restrict__ Wt) {
  int u  = blockIdx.x * 256 + threadIdx.x;   // exactly NCH*PCOL*8 units
  int q  = u & 7;
  int p  = (u >> 3) % PCOL;
  int ch = u / (PCOL * 8);
  int j = p & 63, co = p >> 6;
  const float* src = W + (size_t)(j * 3 + co) * 16576 + ch * 64 + q * 8;
  float4 fa = *(const float4*)src;
  float4 fb = *(const float4*)(src + 4);
  uint4 v;
  v.x = pk2(fa.x, fa.y); v.y = pk2(fa.z, fa.w);
  v.z = pk2(fb.x, fb.y); v.w = pk2(fb.z, fb.w);
  int wid = p / 48, within = p % 48;
  int nt = within >> 4, lr = within & 15;
  int ks = q >> 2,      lq = q & 3;
  int r = nt * 2 + ks, lane = lq * 16 + lr;
  ((uint4*)Wt)[(size_t)ch * 1536 + wid * 384 + r * 64 + lane] = v;
}

// ---- kernel 2: bf16 MFMA GEMM, BK=128 at CONSTANT occupancy ----------------
// reg-B (no B LDS) => A-LDS only 32KB total => still 2 blocks/CU, but HALF
// the barrier phases of the 80.7µs kernel (pairs of 64-k chunks per phase).
// Isolates: per-phase fixed cost (m233) at fixed occupancy. A: depth-2 pair
// prefetch; B: single reg set reloaded after use (B-depth proven null).
__global__ __launch_bounds__(256, 2)
void gemm_bf16(const float* __restrict__ x, const float* __restrict__ seeds,
               const u16* __restrict__ Wt, float* __restrict__ dst,
               const float* __restrict__ bias, int S) {
  __shared__ __align__(16) u16 ldsA[2][8192];   // per buf: two 64x64 A subtiles
  const int tid  = threadIdx.x;
  const int lane = tid & 63;
  const int wid  = tid >> 6;
  const int bid  = blockIdx.x;
  int mblk, ksp;
  if (S == 8) { ksp = bid & 7;  mblk = bid >> 3; }   // XCD-pinned split
  else        { mblk = bid & 63; ksp = bid >> 6; }
  const int n  = mblk >> 2;
  const int t0 = (mblk & 3) << 6;
  const int c0 = (NCH * ksp) / S;
  const int c1 = (NCH * (ksp + 1)) / S;

  const int q0 = tid & 7;          // A staging: 8-float unit within row
  const int m0 = tid >> 3;         // A staging: rows m0, m0+32
  const int lr = lane & 15, lq = lane >> 4;

  f32x4 acc[4][3] = {};

  struct ASet { float4 r0a, r0b, r1a, r1b, r2a, r2b, r3a, r3b; };  // pair
  ASet AX, AY;
  uint4 Breg[12];                  // pair: r = sub*6 + nt*2 + ks (const-idx)

  const char* bbase = (const char*)Wt + wid * 6144 + lane * 16;

  auto arow = [&](int ch, int mrow) -> const float* {
    if (ch < NCHX)
      return x + (((size_t)n * CIN + ch) * TDIM + (t0 + mrow)) * VDIM + q0 * 8;
    return seeds + ((size_t)n * TDIM + (t0 + mrow)) * 192 + (ch - NCHX) * 64 + q0 * 8;
  };
  auto Ai = [&](int cc, ASet& s) {   // pair base cc; sub1 guarded
    const float* a0 = arow(cc, m0);
    const float* a1 = arow(cc, m0 + 32);
    s.r0a = *(const float4*)a0; s.r0b = *(const float4*)(a0 + 4);
    s.r1a = *(const float4*)a1; s.r1b = *(const float4*)(a1 + 4);
    if (cc + 1 < c1) {
      const float* b0 = arow(cc + 1, m0);
      const float* b1 = arow(cc + 1, m0 + 32);
      s.r2a = *(const float4*)b0; s.r2b = *(const float4*)(b0 + 4);
      s.r3a = *(const float4*)b1; s.r3b = *(const float4*)(b1 + 4);
    }
  };
  auto Bi = [&](int cc) {            // pair: 2 x 6 coalesced 1KB/wave loads
    const uint4* g0 = (const uint4*)(bbase + (size_t)cc * 24576);
    Breg[0] = g0[0];   Breg[1] = g0[64];  Breg[2] = g0[128];
    Breg[3] = g0[192]; Breg[4] = g0[256]; Breg[5] = g0[320];
    if (cc + 1 < c1) {
      const uint4* g1 = (const uint4*)(bbase + (size_t)(cc + 1) * 24576);
      Breg[6]  = g1[0];   Breg[7]  = g1[64];  Breg[8]  = g1[128];
      Breg[9]  = g1[192]; Breg[10] = g1[256]; Breg[11] = g1[320];
    }
  };
  auto CONV = [&](const ASet& s, int buf, int cc) {  // pack + swizzled ds_write
    uint4 v;
    v.x = pk2(s.r0a.x, s.r0a.y); v.y = pk2(s.r0a.z, s.r0a.w);
    v.z = pk2(s.r0b.x, s.r0b.y); v.w = pk2(s.r0b.z, s.r0b.w);
    ((uint4*)&ldsA[buf][0])[m0 * 8 + (q0 ^ (m0 & 7))] = v;
    int m1 = m0 + 32;
    v.x = pk2(s.r1a.x, s.r1a.y); v.y = pk2(s.r1a.z, s.r1a.w);
    v.z = pk2(s.r1b.x, s.r1b.y); v.w = pk2(s.r1b.z, s.r1b.w);
    ((uint4*)&ldsA[buf][0])[m1 * 8 + (q0 ^ (m1 & 7))] = v;
    if (cc + 1 < c1) {
      v.x = pk2(s.r2a.x, s.r2a.y); v.y = pk2(s.r2a.z, s.r2a.w);
      v.z = pk2(s.r2b.x, s.r2b.y); v.w = pk2(s.r2b.z, s.r2b.w);
      ((uint4*)&ldsA[buf][4096])[m0 * 8 + (q0 ^ (m0 & 7))] = v;
      v.x = pk2(s.r3a.x, s.r3a.y); v.y = pk2(s.r3a.z, s.r3a.w);
      v.z = pk2(s.r3b.x, s.r3b.y); v.w = pk2(s.r3b.z, s.r3b.w);
      ((uint4*)&ldsA[buf][4096])[m1 * 8 + (q0 ^ (m1 & 7))] = v;
    }
  };

  auto COMPUTE = [&](int buf, bool hasSub1) {   // up to 48 MFMA / 16 ds_read
    #pragma unroll
    for (int sub = 0; sub < 2; ++sub) {
      if (sub == 1 && !hasSub1) break;
      const u16* L = &ldsA[buf][sub * 4096];
      #pragma unroll
      for (int ks = 0; ks < 2; ++ks) {
        const int q = ks * 4 + lq;
        bf16x8 af[4];
        #pragma unroll
        for (int mt = 0; mt < 4; ++mt) {
          int m = mt * 16 + lr;
          af[mt] = *(const bf16x8*)(L + (m * 8 + (q ^ (m & 7))) * 8);
        }
        bf16x8 b0 = __builtin_bit_cast(bf16x8, Breg[sub * 6 + 0 + ks]);
        bf16x8 b1 = __builtin_bit_cast(bf16x8, Breg[sub * 6 + 2 + ks]);
        bf16x8 b2 = __builtin_bit_cast(bf16x8, Breg[sub * 6 + 4 + ks]);
        #pragma unroll
        for (int mt = 0; mt < 4; ++mt) {
          acc[mt][0] = __builtin_amdgcn_mfma_f32_16x16x32_bf16(af[mt], b0, acc[mt][0], 0, 0, 0);
          acc[mt][1] = __builtin_amdgcn_mfma_f32_16x16x32_bf16(af[mt], b1, acc[mt][1], 0, 0, 0);
          acc[mt][2] = __builtin_amdgcn_mfma_f32_16x16x32_bf16(af[mt], b2, acc[mt][2], 0, 0, 0);
        }
      }
    }
  };

  // ---- prologue: B(pair c0)->regs; A(pair c0),A(pair c0+2)->regs ----------
  Bi(c0);
  Ai(c0, AX);
  if (c0 + 2 < c1) Ai(c0 + 2, AY);
  __builtin_amdgcn_sched_barrier(0);
  CONV(AX, 0, c0);                   // compiler auto-waits AX loads
  asm volatile("s_waitcnt lgkmcnt(0)" ::: "memory");
  __builtin_amdgcn_sched_barrier(0);
  __builtin_amdgcn_s_barrier();
  __builtin_amdgcn_sched_barrier(0);

  // ---- main loop over pairs, unrolled x2 (named A-sets; rule #20) ---------
#define PHASE(PAR, AP, AN)                                                    \
  {                                                                           \
    const bool hasN  = (cc + 2 < c1);                                         \
    const bool hasNN = (cc + 4 < c1);                                         \
    if (hasNN) Ai(cc + 4, AN);                                                \
    __builtin_amdgcn_sched_barrier(0);                                        \
    COMPUTE(PAR, cc + 1 < c1);                                                \
    __builtin_amdgcn_sched_barrier(0);                                        \
    if (hasN) Bi(cc + 2);          /* reload just-consumed B set */           \
    if (!hasN) break;                                                         \
    CONV(AP, (PAR) ^ 1, cc + 2);   /* auto-wait drains A(pair cc+2) */        \
    asm volatile("s_waitcnt lgkmcnt(0)" ::: "memory");                        \
    __builtin_amdgcn_sched_barrier(0);                                        \
    __builtin_amdgcn_s_barrier();                                             \
    __builtin_amdgcn_sched_barrier(0);                                        \
  }

  int cc = c0;
  while (true) {
    PHASE(0, AY, AX)     // compute pair cc (even parity)
    cc += 2;
    PHASE(1, AX, AY)     // compute pair cc (odd parity)
    cc += 2;
  }
#undef PHASE

  // epilogue: C layout col=lane&15, row=(lane>>4)*4+reg  [measured m89/m91]
  float* dbase = dst + (size_t)ksp * MTOT * PCOL;
  #pragma unroll
  for (int mt = 0; mt < 4; ++mt)
    #pragma unroll
    for (int nt = 0; nt < 3; ++nt) {
      int col = wid * 48 + nt * 16 + lr;
      float bv = bias ? bias[(col & 63) * 3 + (col >> 6)] : 0.f;
      #pragma unroll
      for (int r = 0; r < 4; ++r) {
        int row = mblk * 64 + mt * 16 + lq * 4 + r;
        dbase[(size_t)row * PCOL + col] = acc[mt][nt][r] + bv;
      }
    }
}

// ---- kernel 3: deterministic K-split reduction + bias ----------------------
__global__ void reduce_k(const float* __restrict__ part, const float* __restrict__ b,
                         float* __restrict__ out, int S) {
  int i4 = (blockIdx.x * 256 + threadIdx.x) * 4;   // exact: MTOT*PCOL/4 threads
  float4 a = *(const float4*)&part[i4];
  for (int s = 1; s < S; ++s) {
    const float4 v = *(const float4*)&part[(size_t)s * (MTOT * PCOL) + i4];
    a.x += v.x; a.y += v.y; a.z += v.z; a.w += v.w;
  }
  int p0 = i4 % PCOL;
  a.x += b[((p0 + 0) & 63) * 3 + ((p0 + 0) >> 6)];
  a.y += b[((p0 + 1) & 63) * 3 + ((p0 + 1) >> 6)];
  a.z += b[((p0 + 2) & 63) * 3 + ((p0 + 2) >> 6)];
  a.w += b[((p0 + 3) & 63) * 3 + ((p0 + 3) >> 6)];
  *(float4*)&out[i4] = a;
}

// ---- insurance fallback if ws too small for the Wt image (unlikely) --------
__global__ void fallback_k(const float* __restrict__ x, const float* __restrict__ seeds,
                           const float* __restrict__ W, const float* __restrict__ b,
                           float* __restrict__ out) {
  __shared__ float mk[512];
  int m = blockIdx.x, n = m >> 8, t = m & 255, p = threadIdx.x;
  float acc = 0.f;
  for (int k0 = 0; k0 < 16576; k0 += 512) {
    int kn = min(512, 16576 - k0);
    __syncthreads();
    for (int i = threadIdx.x; i < kn; i += 256) {
      int k = k0 + i;
      mk[i] = (k < 16384)
                ? x[(((size_t)n * 256 + (k >> 6)) * 256 + t) * 64 + (k & 63)]
                : seeds[((size_t)n * 256 + t) * 192 + (k - 16384)];
    }
    __syncthreads();
    if (p < PCOL) {
      const float* wr = W + (size_t)((p & 63) * 3 + (p >> 6)) * 16576 + k0;
      for (int i = 0; i < kn; ++i) acc += mk[i] * wr[i];
    }
  }
  if (p < PCOL) out[(size_t)m * PCOL + p] = acc + b[(p & 63) * 3 + (p >> 6)];
}

extern "C" void kernel_launch(void* const* d_in, const int* in_sizes, int n_in,
                              void* d_out, int out_size, void* d_ws, size_t ws_size,
                              hipStream_t stream) {
  (void)in_sizes; (void)n_in; (void)out_size;
  const float* x     = (const float*)d_in[0];
  const float* seeds = (const float*)d_in[1];
  const float* W     = (const float*)d_in[2];
  const float* b     = (const float*)d_in[3];
  float* out = (float*)d_out;

  if (ws_size < WT_BYTES) {              // no room for bf16 weight image
    fallback_k<<<dim3(MTOT), dim3(256), 0, stream>>>(x, seeds, W, b, out);
    return;
  }
  u16* Wt = (u16*)d_ws;
  int S = 8;                             // K-split for grid = 64*S blocks
  while (S > 1 && WT_BYTES + (size_t)S * MTOT * PCOL * 4 > ws_size) S >>= 1;
  if (WT_BYTES + (size_t)S * MTOT * PCOL * 4 > ws_size) S = 1;

  prep_w<<<dim3((NCH * PCOL * 8) / 256), dim3(256), 0, stream>>>(W, Wt);
  if (S == 1) {
    gemm_bf16<<<dim3(64), dim3(256), 0, stream>>>(x, seeds, Wt, out, b, 1);
  } else {
    float* part = (float*)((char*)d_ws + WT_BYTES);
    gemm_bf16<<<dim3(64 * S), dim3(256), 0, stream>>>(x, seeds, Wt, part, nullptr, S);
    reduce_k<<<dim3(MTOT * PCOL / 4 / 256), dim3(256), 0, stream>>>(part, b, out, S);
  }
}

// Round 14
// 77.146 us; speedup vs baseline: 3.2580x; 1.0125x over previous
//
#include <hip/hip_runtime.h>
#include <hip/hip_bf16.h>

typedef unsigned short u16;
typedef unsigned int   u32;
typedef __attribute__((ext_vector_type(8))) short bf16x8;
typedef __attribute__((ext_vector_type(4))) float f32x4;

#define NB    16
#define CIN   256
#define TDIM  256
#define VDIM  64
#define PCOL  192          // output columns = C_OUT*NEW_NODES, p = co*64 + j
#define NCHX  256          // x-part K chunks (64 wide each)
#define NCH   259          // + 3 seed chunks ; K = 16576
#define MTOT  4096         // N*T
#define CHUNK_U16 12288    // PCOL*64 bf16 per chunk
#define WT_BYTES ((size_t)NCH * CHUNK_U16 * 2)   // 6,365,184 B

// ---- helpers ---------------------------------------------------------------
__device__ __forceinline__ u16 f2bf(float f) {            // f32 -> bf16 RNE
  u32 u = __builtin_bit_cast(u32, f);
  u32 r = u + 0x7fffu + ((u >> 16) & 1u);
  return (u16)(r >> 16);
}
__device__ __forceinline__ u32 pk2(float a, float b) {
  return (u32)f2bf(a) | ((u32)f2bf(b) << 16);
}

// ---- kernel 1: W f32 -> bf16, WAVE-LOAD-ORDER image (unchanged) ------------
// granule position = [ch][wid][r=nt*2+ks][lane]; each per-wave GEMM B-load is
// one contiguous 1KB segment.
__global__ void prep_w(const float* __restrict__ W, u16* __restrict__ Wt) {
  int u  = blockIdx.x * 256 + threadIdx.x;   // exactly NCH*PCOL*8 units
  int q  = u & 7;
  int p  = (u >> 3) % PCOL;
  int ch = u / (PCOL * 8);
  int j = p & 63, co = p >> 6;
  const float* src = W + (size_t)(j * 3 + co) * 16576 + ch * 64 + q * 8;
  float4 fa = *(const float4*)src;
  float4 fb = *(const float4*)(src + 4);
  uint4 v;
  v.x = pk2(fa.x, fa.y); v.y = pk2(fa.z, fa.w);
  v.z = pk2(fb.x, fb.y); v.w = pk2(fb.z, fb.w);
  int wid = p / 48, within = p % 48;
  int nt = within >> 4, lr = within & 15;
  int ks = q >> 2,      lq = q & 3;
  int r = nt * 2 + ks, lane = lq * 16 + lr;
  ((uint4*)Wt)[(size_t)ch * 1536 + wid * 384 + r * 64 + lane] = v;
}

// ---- kernel 2: bf16 MFMA GEMM, BK=128 @ 2 blocks/CU (r13, 78.1µs) + T5 ----
// s_setprio(1) wrapped around the MFMA cluster: with 2 independent blocks/CU
// whose phases drift, the CU scheduler can favor the block in its MFMA phase
// over the block issuing stage loads (T5 role-diversity condition).
__global__ __launch_bounds__(256, 2)
void gemm_bf16(const float* __restrict__ x, const float* __restrict__ seeds,
               const u16* __restrict__ Wt, float* __restrict__ dst,
               const float* __restrict__ bias, int S) {
  __shared__ __align__(16) u16 ldsA[2][8192];   // per buf: two 64x64 A subtiles
  const int tid  = threadIdx.x;
  const int lane = tid & 63;
  const int wid  = tid >> 6;
  const int bid  = blockIdx.x;
  int mblk, ksp;
  if (S == 8) { ksp = bid & 7;  mblk = bid >> 3; }   // XCD-pinned split
  else        { mblk = bid & 63; ksp = bid >> 6; }
  const int n  = mblk >> 2;
  const int t0 = (mblk & 3) << 6;
  const int c0 = (NCH * ksp) / S;
  const int c1 = (NCH * (ksp + 1)) / S;

  const int q0 = tid & 7;          // A staging: 8-float unit within row
  const int m0 = tid >> 3;         // A staging: rows m0, m0+32
  const int lr = lane & 15, lq = lane >> 4;

  f32x4 acc[4][3] = {};

  struct ASet { float4 r0a, r0b, r1a, r1b, r2a, r2b, r3a, r3b; };  // pair
  ASet AX, AY;
  uint4 Breg[12];                  // pair: r = sub*6 + nt*2 + ks (const-idx)

  const char* bbase = (const char*)Wt + wid * 6144 + lane * 16;

  auto arow = [&](int ch, int mrow) -> const float* {
    if (ch < NCHX)
      return x + (((size_t)n * CIN + ch) * TDIM + (t0 + mrow)) * VDIM + q0 * 8;
    return seeds + ((size_t)n * TDIM + (t0 + mrow)) * 192 + (ch - NCHX) * 64 + q0 * 8;
  };
  auto Ai = [&](int cc, ASet& s) {   // pair base cc; sub1 guarded
    const float* a0 = arow(cc, m0);
    const float* a1 = arow(cc, m0 + 32);
    s.r0a = *(const float4*)a0; s.r0b = *(const float4*)(a0 + 4);
    s.r1a = *(const float4*)a1; s.r1b = *(const float4*)(a1 + 4);
    if (cc + 1 < c1) {
      const float* b0 = arow(cc + 1, m0);
      const float* b1 = arow(cc + 1, m0 + 32);
      s.r2a = *(const float4*)b0; s.r2b = *(const float4*)(b0 + 4);
      s.r3a = *(const float4*)b1; s.r3b = *(const float4*)(b1 + 4);
    }
  };
  auto Bi = [&](int cc) {            // pair: 2 x 6 coalesced 1KB/wave loads
    const uint4* g0 = (const uint4*)(bbase + (size_t)cc * 24576);
    Breg[0] = g0[0];   Breg[1] = g0[64];  Breg[2] = g0[128];
    Breg[3] = g0[192]; Breg[4] = g0[256]; Breg[5] = g0[320];
    if (cc + 1 < c1) {
      const uint4* g1 = (const uint4*)(bbase + (size_t)(cc + 1) * 24576);
      Breg[6]  = g1[0];   Breg[7]  = g1[64];  Breg[8]  = g1[128];
      Breg[9]  = g1[192]; Breg[10] = g1[256]; Breg[11] = g1[320];
    }
  };
  auto CONV = [&](const ASet& s, int buf, int cc) {  // pack + swizzled ds_write
    uint4 v;
    v.x = pk2(s.r0a.x, s.r0a.y); v.y = pk2(s.r0a.z, s.r0a.w);
    v.z = pk2(s.r0b.x, s.r0b.y); v.w = pk2(s.r0b.z, s.r0b.w);
    ((uint4*)&ldsA[buf][0])[m0 * 8 + (q0 ^ (m0 & 7))] = v;
    int m1 = m0 + 32;
    v.x = pk2(s.r1a.x, s.r1a.y); v.y = pk2(s.r1a.z, s.r1a.w);
    v.z = pk2(s.r1b.x, s.r1b.y); v.w = pk2(s.r1b.z, s.r1b.w);
    ((uint4*)&ldsA[buf][0])[m1 * 8 + (q0 ^ (m1 & 7))] = v;
    if (cc + 1 < c1) {
      v.x = pk2(s.r2a.x, s.r2a.y); v.y = pk2(s.r2a.z, s.r2a.w);
      v.z = pk2(s.r2b.x, s.r2b.y); v.w = pk2(s.r2b.z, s.r2b.w);
      ((uint4*)&ldsA[buf][4096])[m0 * 8 + (q0 ^ (m0 & 7))] = v;
      v.x = pk2(s.r3a.x, s.r3a.y); v.y = pk2(s.r3a.z, s.r3a.w);
      v.z = pk2(s.r3b.x, s.r3b.y); v.w = pk2(s.r3b.z, s.r3b.w);
      ((uint4*)&ldsA[buf][4096])[m1 * 8 + (q0 ^ (m1 & 7))] = v;
    }
  };

  auto COMPUTE = [&](int buf, bool hasSub1) {   // up to 48 MFMA / 16 ds_read
    #pragma unroll
    for (int sub = 0; sub < 2; ++sub) {
      if (sub == 1 && !hasSub1) break;
      const u16* L = &ldsA[buf][sub * 4096];
      #pragma unroll
      for (int ks = 0; ks < 2; ++ks) {
        const int q = ks * 4 + lq;
        bf16x8 af[4];
        #pragma unroll
        for (int mt = 0; mt < 4; ++mt) {
          int m = mt * 16 + lr;
          af[mt] = *(const bf16x8*)(L + (m * 8 + (q ^ (m & 7))) * 8);
        }
        bf16x8 b0 = __builtin_bit_cast(bf16x8, Breg[sub * 6 + 0 + ks]);
        bf16x8 b1 = __builtin_bit_cast(bf16x8, Breg[sub * 6 + 2 + ks]);
        bf16x8 b2 = __builtin_bit_cast(bf16x8, Breg[sub * 6 + 4 + ks]);
        __builtin_amdgcn_s_setprio(1);          // T5: favor MFMA-phase wave
        #pragma unroll
        for (int mt = 0; mt < 4; ++mt) {
          acc[mt][0] = __builtin_amdgcn_mfma_f32_16x16x32_bf16(af[mt], b0, acc[mt][0], 0, 0, 0);
          acc[mt][1] = __builtin_amdgcn_mfma_f32_16x16x32_bf16(af[mt], b1, acc[mt][1], 0, 0, 0);
          acc[mt][2] = __builtin_amdgcn_mfma_f32_16x16x32_bf16(af[mt], b2, acc[mt][2], 0, 0, 0);
        }
        __builtin_amdgcn_s_setprio(0);
      }
    }
  };

  // ---- prologue: B(pair c0)->regs; A(pair c0),A(pair c0+2)->regs ----------
  Bi(c0);
  Ai(c0, AX);
  if (c0 + 2 < c1) Ai(c0 + 2, AY);
  __builtin_amdgcn_sched_barrier(0);
  CONV(AX, 0, c0);                   // compiler auto-waits AX loads
  asm volatile("s_waitcnt lgkmcnt(0)" ::: "memory");
  __builtin_amdgcn_sched_barrier(0);
  __builtin_amdgcn_s_barrier();
  __builtin_amdgcn_sched_barrier(0);

  // ---- main loop over pairs, unrolled x2 (named A-sets; rule #20) ---------
#define PHASE(PAR, AP, AN)                                                    \
  {                                                                           \
    const bool hasN  = (cc + 2 < c1);                                         \
    const bool hasNN = (cc + 4 < c1);                                         \
    if (hasNN) Ai(cc + 4, AN);                                                \
    __builtin_amdgcn_sched_barrier(0);                                        \
    COMPUTE(PAR, cc + 1 < c1);                                                \
    __builtin_amdgcn_sched_barrier(0);                                        \
    if (hasN) Bi(cc + 2);          /* reload just-consumed B set */           \
    if (!hasN) break;                                                         \
    CONV(AP, (PAR) ^ 1, cc + 2);   /* auto-wait drains A(pair cc+2) */        \
    asm volatile("s_waitcnt lgkmcnt(0)" ::: "memory");                        \
    __builtin_amdgcn_sched_barrier(0);                                        \
    __builtin_amdgcn_s_barrier();                                             \
    __builtin_amdgcn_sched_barrier(0);                                        \
  }

  int cc = c0;
  while (true) {
    PHASE(0, AY, AX)     // compute pair cc (even parity)
    cc += 2;
    PHASE(1, AX, AY)     // compute pair cc (odd parity)
    cc += 2;
  }
#undef PHASE

  // epilogue: C layout col=lane&15, row=(lane>>4)*4+reg  [measured m89/m91]
  float* dbase = dst + (size_t)ksp * MTOT * PCOL;
  #pragma unroll
  for (int mt = 0; mt < 4; ++mt)
    #pragma unroll
    for (int nt = 0; nt < 3; ++nt) {
      int col = wid * 48 + nt * 16 + lr;
      float bv = bias ? bias[(col & 63) * 3 + (col >> 6)] : 0.f;
      #pragma unroll
      for (int r = 0; r < 4; ++r) {
        int row = mblk * 64 + mt * 16 + lq * 4 + r;
        dbase[(size_t)row * PCOL + col] = acc[mt][nt][r] + bv;
      }
    }
}

// ---- kernel 3: deterministic K-split reduction + bias ----------------------
__global__ void reduce_k(const float* __restrict__ part, const float* __restrict__ b,
                         float* __restrict__ out, int S) {
  int i4 = (blockIdx.x * 256 + threadIdx.x) * 4;   // exact: MTOT*PCOL/4 threads
  float4 a = *(const float4*)&part[i4];
  for (int s = 1; s < S; ++s) {
    const float4 v = *(const float4*)&part[(size_t)s * (MTOT * PCOL) + i4];
    a.x += v.x; a.y += v.y; a.z += v.z; a.w += v.w;
  }
  int p0 = i4 % PCOL;
  a.x += b[((p0 + 0) & 63) * 3 + ((p0 + 0) >> 6)];
  a.y += b[((p0 + 1) & 63) * 3 + ((p0 + 1) >> 6)];
  a.z += b[((p0 + 2) & 63) * 3 + ((p0 + 2) >> 6)];
  a.w += b[((p0 + 3) & 63) * 3 + ((p0 + 3) >> 6)];
  *(float4*)&out[i4] = a;
}

// ---- insurance fallback if ws too small for the Wt image (unlikely) --------
__global__ void fallback_k(const float* __restrict__ x, const float* __restrict__ seeds,
                           const float* __restrict__ W, const float* __restrict__ b,
                           float* __restrict__ out) {
  __shared__ float mk[512];
  int m = blockIdx.x, n = m >> 8, t = m & 255, p = threadIdx.x;
  float acc = 0.f;
  for (int k0 = 0; k0 < 16576; k0 += 512) {
    int kn = min(512, 16576 - k0);
    __syncthreads();
    for (int i = threadIdx.x; i < kn; i += 256) {
      int k = k0 + i;
      mk[i] = (k < 16384)
                ? x[(((size_t)n * 256 + (k >> 6)) * 256 + t) * 64 + (k & 63)]
                : seeds[((size_t)n * 256 + t) * 192 + (k - 16384)];
    }
    __syncthreads();
    if (p < PCOL) {
      const float* wr = W + (size_t)((p & 63) * 3 + (p >> 6)) * 16576 + k0;
      for (int i = 0; i < kn; ++i) acc += mk[i] * wr[i];
    }
  }
  if (p < PCOL) out[(size_t)m * PCOL + p] = acc + b[(p & 63) * 3 + (p >> 6)];
}

extern "C" void kernel_launch(void* const* d_in, const int* in_sizes, int n_in,
                              void* d_out, int out_size, void* d_ws, size_t ws_size,
                              hipStream_t stream) {
  (void)in_sizes; (void)n_in; (void)out_size;
  const float* x     = (const float*)d_in[0];
  const float* seeds = (const float*)d_in[1];
  const float* W     = (const float*)d_in[2];
  const float* b     = (const float*)d_in[3];
  float* out = (float*)d_out;

  if (ws_size < WT_BYTES) {              // no room for bf16 weight image
    fallback_k<<<dim3(MTOT), dim3(256), 0, stream>>>(x, seeds, W, b, out);
    return;
  }
  u16* Wt = (u16*)d_ws;
  int S = 8;                             // K-split for grid = 64*S blocks
  while (S > 1 && WT_BYTES + (size_t)S * MTOT * PCOL * 4 > ws_size) S >>= 1;
  if (WT_BYTES + (size_t)S * MTOT * PCOL * 4 > ws_size) S = 1;

  prep_w<<<dim3((NCH * PCOL * 8) / 256), dim3(256), 0, stream>>>(W, Wt);
  if (S == 1) {
    gemm_bf16<<<dim3(64), dim3(256), 0, stream>>>(x, seeds, Wt, out, b, 1);
  } else {
    float* part = (float*)((char*)d_ws + WT_BYTES);
    gemm_bf16<<<dim3(64 * S), dim3(256), 0, stream>>>(x, seeds, Wt, part, nullptr, S);
    reduce_k<<<dim3(MTOT * PCOL / 4 / 256), dim3(256), 0, stream>>>(part, b, out, S);
  }
}